// Round 1
// baseline (1512.177 us; speedup 1.0000x reference)
//
#include <hip/hip_runtime.h>
#include <math.h>

// Problem dims
constexpr int CB = 64;        // batch
constexpr int CD = 3072;      // feature dim (3*32*32)
constexpr int CN = 50000;     // train rows
constexpr int NPAD = 50176;   // 1568 * 32
constexpr int TK = 32;        // k-tile (both GEMMs)

// GEMM1: tile 64(b) x 32(n), grid NB1 = 1568 blocks (~6.1/CU -> ~24 waves/CU)
constexpr int NB1 = NPAD / 32;   // 1568 n-tiles == chunk-max granularity
// GEMM2: tile 64(b) x 64(d), split-K over n: grid (48, 32) = 1536 = exactly 6/CU
constexpr int TD2 = 64;
constexpr int G2 = 32;
constexpr int NC2 = NPAD / G2;   // 1568 n per chunk
constexpr int NK2 = NC2 / TK;    // 49 k-tiles per chunk

// ws float offsets
constexpr int OFF_XSQ = 0;
constexpr int OFF_A = 64;
constexpr int OFF_CDENO = 128;
constexpr int OFF_CX = 192;
constexpr int OFF_CXH = 256;
constexpr int OFF_PSUM = 320;                         // 64*4 softmax partial sums
constexpr int OFF_CHM = 1024;                         // 64*1568 chunk maxes
constexpr size_t OFF_NORM = 101376;                   // 1024 + 64*1568; 64*50176 floats
constexpr size_t OFF_P = OFF_NORM + (size_t)CB * NPAD;  // 3,312,640; G2*64*3072 floats
// total ws = (3312640 + 32*64*3072) * 4B = 38.4 MB

// ---------------- Kernel 1: coefficients + x_sq ----------------
__global__ __launch_bounds__(64) void prep_kernel(
    const float* __restrict__ x, const float* __restrict__ acp,
    const int* __restrict__ t, float* __restrict__ wsf) {
  const int b = blockIdx.x;
  const int tid = threadIdx.x;
  float s = 0.f;
  for (int i = tid; i < CD; i += 64) {
    float v = x[b * CD + i];
    s += v * v;
  }
#pragma unroll
  for (int o = 1; o < 64; o <<= 1) s += __shfl_xor(s, o);
  if (tid == 0) {
    float ac = acp[t[b]];
    float a = sqrtf(ac);
    float om = 1.0f - ac;
    float sq = sqrtf(om);
    wsf[OFF_XSQ + b] = s;
    wsf[OFF_A + b] = a;
    wsf[OFF_CDENO + b] = -0.5f / om;
    wsf[OFF_CX + b] = 1.0f / sq;
    wsf[OFF_CXH + b] = a / sq;
  }
}

// ---------------- Kernel 2: norm = coef_deno*(x_sq - 2a*cross + a^2*tr_sq) ----------------
// 1568 blocks x 256 thr. Tile 64(b) x 32(n); per-thread 2x4; register-prefetch dbuf.
// LDS strides chosen conflict-free on reads: As[.][68] (b64 read, 16 contiguous words),
// Bs[.][36] (b128 read covers all 32 banks exactly once).
// Also emits per-(b, 32-col-chunk) max for the softmax.
__global__ __launch_bounds__(256, 6) void gemm1_kernel(
    const float* __restrict__ x, const float* __restrict__ train,
    float* __restrict__ wsf) {
  __shared__ float As[TK][68];   // As[k][b], 64 used
  __shared__ float Bs[TK][36];   // Bs[k][n], 32 used
  __shared__ float trsq_s[32];

  const int tid = threadIdx.x;
  const int n0 = blockIdx.x * 32;
  const int r8 = tid >> 3;   // 0..31: staging row; compute b-pair = 2*r8
  const int kq = tid & 7;    // 0..7 : staging k-quad; compute n-quad = 4*kq

  const int gn = n0 + r8;
  const bool tvalid = gn < CN;
  const float* tp = train + (size_t)(tvalid ? gn : 0) * CD + 4 * kq;
  const float* xp = x + (size_t)r8 * CD + 4 * kq;

  // prefetch tile 0
  float4 rx0 = *reinterpret_cast<const float4*>(xp);
  float4 rx1 = *reinterpret_cast<const float4*>(xp + (size_t)32 * CD);
  float4 rt = tvalid ? *reinterpret_cast<const float4*>(tp)
                     : make_float4(0.f, 0.f, 0.f, 0.f);

  float acc[2][4];
#pragma unroll
  for (int i = 0; i < 2; i++)
#pragma unroll
    for (int j = 0; j < 4; j++) acc[i][j] = 0.f;
  float sq = 0.f;  // partial square of train row r8 (k-slice of this thread)

  for (int kt = 0; kt < CD / TK; ++kt) {
    __syncthreads();
    As[4 * kq + 0][r8] = rx0.x;
    As[4 * kq + 1][r8] = rx0.y;
    As[4 * kq + 2][r8] = rx0.z;
    As[4 * kq + 3][r8] = rx0.w;
    As[4 * kq + 0][r8 + 32] = rx1.x;
    As[4 * kq + 1][r8 + 32] = rx1.y;
    As[4 * kq + 2][r8 + 32] = rx1.z;
    As[4 * kq + 3][r8 + 32] = rx1.w;
    Bs[4 * kq + 0][r8] = rt.x;
    Bs[4 * kq + 1][r8] = rt.y;
    Bs[4 * kq + 2][r8] = rt.z;
    Bs[4 * kq + 3][r8] = rt.w;
    sq += rt.x * rt.x + rt.y * rt.y + rt.z * rt.z + rt.w * rt.w;
    __syncthreads();
    if (kt + 1 < CD / TK) {  // issue next-tile loads; consumed after next barrier
      const int ko = (kt + 1) * TK;
      rx0 = *reinterpret_cast<const float4*>(xp + ko);
      rx1 = *reinterpret_cast<const float4*>(xp + (size_t)32 * CD + ko);
      rt = tvalid ? *reinterpret_cast<const float4*>(tp + ko)
                  : make_float4(0.f, 0.f, 0.f, 0.f);
    }
#pragma unroll
    for (int k = 0; k < TK; ++k) {
      float2 a2 = *reinterpret_cast<const float2*>(&As[k][2 * r8]);
      float bv[4];
      *reinterpret_cast<float4*>(bv) =
          *reinterpret_cast<const float4*>(&Bs[k][4 * kq]);
#pragma unroll
      for (int j = 0; j < 4; ++j) {
        acc[0][j] = fmaf(a2.x, bv[j], acc[0][j]);
        acc[1][j] = fmaf(a2.y, bv[j], acc[1][j]);
      }
    }
  }

  // reduce tr_sq across the 8 k-slice lanes of each row
  float s = sq;
  s += __shfl_xor(s, 1);
  s += __shfl_xor(s, 2);
  s += __shfl_xor(s, 4);
  if (kq == 0) trsq_s[r8] = s;
  __syncthreads();

  const int nc = 4 * kq;
  float trq[4] = {trsq_s[nc], trsq_s[nc + 1], trsq_s[nc + 2], trsq_s[nc + 3]};
  const int b0 = 2 * r8;
  float mrow[2];
#pragma unroll
  for (int i = 0; i < 2; ++i) {
    const int b = b0 + i;
    const float a_ = wsf[OFF_A + b];
    const float cdeno = wsf[OFF_CDENO + b];
    const float xsq = wsf[OFF_XSQ + b];
    const float twoa = 2.f * a_;
    const float asq = a_ * a_;
    float outv[4];
#pragma unroll
    for (int j = 0; j < 4; ++j) {
      float nv = cdeno * (xsq - twoa * acc[i][j] + asq * trq[j]);
      outv[j] = (n0 + nc + j < CN) ? nv : -3.0e38f;
    }
    *reinterpret_cast<float4*>(&wsf[OFF_NORM + (size_t)b * NPAD + n0 + nc]) =
        *reinterpret_cast<float4*>(outv);
    float m = fmaxf(fmaxf(outv[0], outv[1]), fmaxf(outv[2], outv[3]));
    m = fmaxf(m, __shfl_xor(m, 1));
    m = fmaxf(m, __shfl_xor(m, 2));
    m = fmaxf(m, __shfl_xor(m, 4));
    mrow[i] = m;
  }
  if (kq == 0) {
    wsf[OFF_CHM + (size_t)b0 * NB1 + blockIdx.x] = mrow[0];
    wsf[OFF_CHM + (size_t)(b0 + 1) * NB1 + blockIdx.x] = mrow[1];
  }
}

// ---------------- Kernel 3: softmax exp pass (max from chunk-maxes) ----------------
// grid (4, 64): each block does a quarter row; stores partial sum psum[b][g].
__global__ __launch_bounds__(256) void softmax_kernel(float* __restrict__ wsf) {
  const int g = blockIdx.x;
  const int b = blockIdx.y;
  const int tid = threadIdx.x;
  const int lane = tid & 63, wid = tid >> 6;
  __shared__ float red[4];
  __shared__ float msh;

  float m = -3.4e38f;
  const float* chm = wsf + OFF_CHM + (size_t)b * NB1;
  for (int i = tid; i < NB1; i += 256) m = fmaxf(m, chm[i]);
#pragma unroll
  for (int o = 1; o < 64; o <<= 1) m = fmaxf(m, __shfl_xor(m, o));
  if (lane == 0) red[wid] = m;
  __syncthreads();
  if (tid == 0) msh = fmaxf(fmaxf(red[0], red[1]), fmaxf(red[2], red[3]));
  __syncthreads();
  m = msh;

  float4* row = reinterpret_cast<float4*>(wsf + OFF_NORM + (size_t)b * NPAD +
                                          (size_t)g * (NPAD / 4));
  float s = 0.f;
  for (int i = tid; i < NPAD / 16; i += 256) {  // 3136 float4 per quarter row
    float4 v = row[i];
    v.x = __expf(v.x - m);
    v.y = __expf(v.y - m);
    v.z = __expf(v.z - m);
    v.w = __expf(v.w - m);
    row[i] = v;
    s += (v.x + v.y) + (v.z + v.w);
  }
#pragma unroll
  for (int o = 1; o < 64; o <<= 1) s += __shfl_xor(s, o);
  __syncthreads();  // red[] reuse
  if (lane == 0) red[wid] = s;
  __syncthreads();
  if (tid == 0) wsf[OFF_PSUM + 4 * b + g] = (red[0] + red[1]) + (red[2] + red[3]);
}

// ---------------- Kernel 4: partial = what @ train (split-K over n) ----------------
// grid (48 d-tiles, 32 chunks) = 1536 blocks. Tile 64(b) x 64(d); per-thread 4x4;
// register-prefetch dbuf. Deterministic partials, reduced in finalize.
__global__ __launch_bounds__(256, 6) void gemm2_kernel(
    const float* __restrict__ train, float* __restrict__ wsf) {
  __shared__ float Ws[TK][68];   // Ws[n][b]
  __shared__ float Ts[TK][68];   // Ts[n][d]

  const int tid = threadIdx.x;
  const int d0 = blockIdx.x * TD2;
  const int g = blockIdx.y;
  const int nbase = g * NC2;
  const int ty = tid >> 4;   // 0..15: b = 4*ty + i
  const int tx = tid & 15;   // 0..15: d = 4*tx + j
  const int wb = tid >> 3;   // 0..31 (+32): w staging row
  const int wq = tid & 7;    // w staging n-quad
  const int tn = tid >> 4;   // 0..15 (+16): train staging row
  const int tdq = tid & 15;  // train staging d-quad

  const float* wp = wsf + OFF_NORM + (size_t)wb * NPAD + nbase + 4 * wq;
  const float* tp0 = train + d0 + 4 * tdq;

  float4 rw0, rw1, rt0, rt1;
  {
    rw0 = *reinterpret_cast<const float4*>(wp);
    rw1 = *reinterpret_cast<const float4*>(wp + (size_t)32 * NPAD);
    int g0 = nbase + tn;
    int g1 = nbase + tn + 16;
    if (g0 >= CN) g0 = CN - 1;  // w==0 there; just avoid OOB
    if (g1 >= CN) g1 = CN - 1;
    rt0 = *reinterpret_cast<const float4*>(tp0 + (size_t)g0 * CD);
    rt1 = *reinterpret_cast<const float4*>(tp0 + (size_t)g1 * CD);
  }

  float acc[4][4];
#pragma unroll
  for (int i = 0; i < 4; i++)
#pragma unroll
    for (int j = 0; j < 4; j++) acc[i][j] = 0.f;

  for (int kt = 0; kt < NK2; ++kt) {
    __syncthreads();
    Ws[4 * wq + 0][wb] = rw0.x;
    Ws[4 * wq + 1][wb] = rw0.y;
    Ws[4 * wq + 2][wb] = rw0.z;
    Ws[4 * wq + 3][wb] = rw0.w;
    Ws[4 * wq + 0][wb + 32] = rw1.x;
    Ws[4 * wq + 1][wb + 32] = rw1.y;
    Ws[4 * wq + 2][wb + 32] = rw1.z;
    Ws[4 * wq + 3][wb + 32] = rw1.w;
    *reinterpret_cast<float4*>(&Ts[tn][4 * tdq]) = rt0;
    *reinterpret_cast<float4*>(&Ts[tn + 16][4 * tdq]) = rt1;
    __syncthreads();
    if (kt + 1 < NK2) {
      const int ko = (kt + 1) * TK;
      rw0 = *reinterpret_cast<const float4*>(wp + ko);
      rw1 = *reinterpret_cast<const float4*>(wp + (size_t)32 * NPAD + ko);
      int g0 = nbase + ko + tn;
      int g1 = nbase + ko + tn + 16;
      if (g0 >= CN) g0 = CN - 1;
      if (g1 >= CN) g1 = CN - 1;
      rt0 = *reinterpret_cast<const float4*>(tp0 + (size_t)g0 * CD);
      rt1 = *reinterpret_cast<const float4*>(tp0 + (size_t)g1 * CD);
    }
#pragma unroll
    for (int k = 0; k < TK; ++k) {
      float av[4], bv[4];
      *reinterpret_cast<float4*>(av) =
          *reinterpret_cast<const float4*>(&Ws[k][4 * ty]);
      *reinterpret_cast<float4*>(bv) =
          *reinterpret_cast<const float4*>(&Ts[k][4 * tx]);
#pragma unroll
      for (int i = 0; i < 4; ++i)
#pragma unroll
        for (int j = 0; j < 4; ++j) acc[i][j] = fmaf(av[i], bv[j], acc[i][j]);
    }
  }

#pragma unroll
  for (int i = 0; i < 4; ++i) {
    const int b = 4 * ty + i;
    *reinterpret_cast<float4*>(
        &wsf[OFF_P + ((size_t)g * CB + b) * CD + d0 + 4 * tx]) =
        *reinterpret_cast<float4*>(&acc[i][0]);
  }
}

// ---------------- Kernel 5: reduce partials + finalize ----------------
__global__ __launch_bounds__(256) void finalize_kernel(
    const float* __restrict__ x, const float* __restrict__ wsf,
    float* __restrict__ out) {
  const int vi = blockIdx.x * 256 + threadIdx.x;  // float4 idx, 0..49151
  const int b = vi / (CD / 4);
  float4 s = make_float4(0.f, 0.f, 0.f, 0.f);
#pragma unroll 8
  for (int g = 0; g < G2; ++g) {
    const float4 p = *reinterpret_cast<const float4*>(
        &wsf[OFF_P + (size_t)g * CB * CD + 4 * (size_t)vi]);
    s.x += p.x;
    s.y += p.y;
    s.z += p.z;
    s.w += p.w;
  }
  const float l = (wsf[OFF_PSUM + 4 * b] + wsf[OFF_PSUM + 4 * b + 1]) +
                  (wsf[OFF_PSUM + 4 * b + 2] + wsf[OFF_PSUM + 4 * b + 3]);
  const float cx = wsf[OFF_CX + b];
  const float ch = wsf[OFF_CXH + b] / l;
  const float4 xv = *reinterpret_cast<const float4*>(&x[4 * (size_t)vi]);
  float4 o;
  o.x = cx * xv.x - ch * s.x;
  o.y = cx * xv.y - ch * s.y;
  o.z = cx * xv.z - ch * s.z;
  o.w = cx * xv.w - ch * s.w;
  *reinterpret_cast<float4*>(&out[4 * (size_t)vi]) = o;
}

extern "C" void kernel_launch(void* const* d_in, const int* in_sizes, int n_in,
                              void* d_out, int out_size, void* d_ws, size_t ws_size,
                              hipStream_t stream) {
  (void)in_sizes; (void)n_in; (void)out_size; (void)ws_size;
  const float* x = (const float*)d_in[0];
  const float* train = (const float*)d_in[1];
  const float* acp = (const float*)d_in[2];
  const int* t = (const int*)d_in[3];
  float* out = (float*)d_out;
  float* wsf = (float*)d_ws;

  prep_kernel<<<CB, 64, 0, stream>>>(x, acp, t, wsf);
  gemm1_kernel<<<NB1, 256, 0, stream>>>(x, train, wsf);
  softmax_kernel<<<dim3(4, CB), 256, 0, stream>>>(wsf);
  gemm2_kernel<<<dim3(CD / TD2, G2), 256, 0, stream>>>(train, wsf);
  finalize_kernel<<<(CB * CD / 4) / 256, 256, 0, stream>>>(x, wsf, out);
}

// Round 2
// 1051.290 us; speedup vs baseline: 1.4384x; 1.4384x over previous
//
#include <hip/hip_runtime.h>
#include <math.h>

typedef __bf16 bf16x8 __attribute__((ext_vector_type(8)));
typedef float f32x4 __attribute__((ext_vector_type(4)));

// Problem dims
constexpr int CB = 64;
constexpr int CD = 3072;
constexpr int CN = 50000;
constexpr int NPAD = 50176;   // 784*64 = 1568*32

// GEMM2 split
constexpr int TD2 = 128;
constexpr int G2 = 32;
constexpr int NC2 = NPAD / G2;   // 1568
constexpr int NK2 = NC2 / 32;    // 49

// ws offsets (f32/u32 units)
constexpr int OFF_XSQ = 0, OFF_A = 64, OFF_CDENO = 128, OFF_CX = 192, OFF_CXH = 256, OFF_PSUM = 320;
constexpr int OFF_XHI = 1024;                      // 64*3072 bf16 = 98304 u32
constexpr int OFF_XLO = OFF_XHI + 98304;           // 99328
constexpr int OFF_WHI = OFF_XLO + 98304;           // 197632: 64*50176 bf16 = 1605632 u32
constexpr int OFF_WLO = OFF_WHI + 1605632;         // 1803264
constexpr size_t OFF_NORM = (size_t)OFF_WLO + 1605632;  // 3408896: 64*50176 f32
constexpr size_t OFF_P = OFF_NORM;                 // P aliases NORM (NORM dead after softmax)
// ws end = 3408896 + 32*64*3072 = 9700352 f32 = 38.8 MB

static __device__ __forceinline__ unsigned int pk(__bf16 a, __bf16 b) {
  unsigned short ua = __builtin_bit_cast(unsigned short, a);
  unsigned short ub = __builtin_bit_cast(unsigned short, b);
  return (unsigned int)ua | ((unsigned int)ub << 16);
}
static __device__ __forceinline__ void cvt_hl(float4 v, uint2& hi, uint2& lo) {
  __bf16 h0 = (__bf16)v.x, h1 = (__bf16)v.y, h2 = (__bf16)v.z, h3 = (__bf16)v.w;
  __bf16 l0 = (__bf16)(v.x - (float)h0), l1 = (__bf16)(v.y - (float)h1);
  __bf16 l2 = (__bf16)(v.z - (float)h2), l3 = (__bf16)(v.w - (float)h3);
  hi = make_uint2(pk(h0, h1), pk(h2, h3));
  lo = make_uint2(pk(l0, l1), pk(l2, l3));
}

// ---------------- Kernel 1: coefficients + x_sq + split x into bf16 hi/lo ----------------
__global__ __launch_bounds__(64) void prep_kernel(
    const float* __restrict__ x, const float* __restrict__ acp,
    const int* __restrict__ t, float* __restrict__ wsf) {
  const int b = blockIdx.x;
  const int tid = threadIdx.x;
  unsigned short* xh = (unsigned short*)(wsf + OFF_XHI);
  unsigned short* xl = (unsigned short*)(wsf + OFF_XLO);
  float s = 0.f;
  for (int i = tid; i < CD; i += 64) {
    float v = x[b * CD + i];
    s += v * v;
    __bf16 h = (__bf16)v;
    __bf16 l = (__bf16)(v - (float)h);
    xh[(size_t)b * CD + i] = __builtin_bit_cast(unsigned short, h);
    xl[(size_t)b * CD + i] = __builtin_bit_cast(unsigned short, l);
  }
#pragma unroll
  for (int o = 1; o < 64; o <<= 1) s += __shfl_xor(s, o);
  if (tid == 0) {
    float ac = acp[t[b]];
    float a = sqrtf(ac);
    float om = 1.0f - ac;
    float sq = sqrtf(om);
    wsf[OFF_XSQ + b] = s;
    wsf[OFF_A + b] = a;
    wsf[OFF_CDENO + b] = -0.5f / om;
    wsf[OFF_CX + b] = 1.0f / sq;
    wsf[OFF_CXH + b] = a / sq;
  }
}

// ---------------- Kernel 2: norm via split-bf16 MFMA ----------------
// C = x @ train^T (NT GEMM). Block: 64b x 64n, 256 thr (4 waves 2x2 of 32x32),
// K-step 32, 3x mfma_f32_16x16x32_bf16 per tile (hh + hl + lh).
// LDS rows padded to 80B: frag reads <=2-way bank aliasing (free).
__global__ __launch_bounds__(256, 4) void gemm1_kernel(
    const float* __restrict__ train, float* __restrict__ wsf) {
  __shared__ __align__(16) unsigned int Ah[64 * 20], Al[64 * 20];
  __shared__ __align__(16) unsigned int Bh[64 * 20], Bl[64 * 20];
  __shared__ float trsq_s[64], cAs[64], cDs[64], cXs[64];

  const int tid = threadIdx.x;
  const int n0 = blockIdx.x * 64;
  if (tid < 64) {
    cAs[tid] = wsf[OFF_A + tid];
    cDs[tid] = wsf[OFF_CDENO + tid];
    cXs[tid] = wsf[OFF_XSQ + tid];
  }

  const unsigned int* xh32 = (const unsigned int*)(wsf + OFF_XHI);
  const unsigned int* xl32 = (const unsigned int*)(wsf + OFF_XLO);

  const int xr = tid >> 2, xq = tid & 3;    // x staging: row 0..63, 16B-quad
  const int tn0 = tid >> 3, tkq = tid & 7;  // train staging: rows tn0, tn0+32
  const int gna = n0 + tn0, gnb = n0 + tn0 + 32;
  const float* tpa = train + (size_t)(gna < CN ? gna : 0) * CD + 4 * tkq;
  const float* tpb = train + (size_t)(gnb < CN ? gnb : 0) * CD + 4 * tkq;

  // prefetch k-tile 0
  uint4 pxh = *(const uint4*)&xh32[xr * 1536 + xq * 4];
  uint4 pxl = *(const uint4*)&xl32[xr * 1536 + xq * 4];
  float4 pt0 = *(const float4*)tpa;
  float4 pt1 = *(const float4*)tpb;

  f32x4 acc[2][2];
#pragma unroll
  for (int i = 0; i < 2; ++i)
#pragma unroll
    for (int j = 0; j < 2; ++j) acc[i][j] = (f32x4){0.f, 0.f, 0.f, 0.f};
  float sq0 = 0.f, sq1 = 0.f;

  const int lane = tid & 63, w = tid >> 6;
  const int wm = w >> 1, wn = w & 1, lr = lane & 15, lg = lane >> 4;

  for (int kt = 0; kt < CD / 32; ++kt) {
    __syncthreads();
    *(uint4*)&Ah[xr * 20 + xq * 4] = pxh;
    *(uint4*)&Al[xr * 20 + xq * 4] = pxl;
    uint2 h2, l2;
    cvt_hl(pt0, h2, l2);
    *(uint2*)&Bh[tn0 * 20 + tkq * 2] = h2;
    *(uint2*)&Bl[tn0 * 20 + tkq * 2] = l2;
    sq0 += pt0.x * pt0.x + pt0.y * pt0.y + pt0.z * pt0.z + pt0.w * pt0.w;
    cvt_hl(pt1, h2, l2);
    *(uint2*)&Bh[(tn0 + 32) * 20 + tkq * 2] = h2;
    *(uint2*)&Bl[(tn0 + 32) * 20 + tkq * 2] = l2;
    sq1 += pt1.x * pt1.x + pt1.y * pt1.y + pt1.z * pt1.z + pt1.w * pt1.w;
    __syncthreads();
    if (kt + 1 < CD / 32) {
      const int ko = (kt + 1) * 32;
      pxh = *(const uint4*)&xh32[xr * 1536 + ko / 2 + xq * 4];
      pxl = *(const uint4*)&xl32[xr * 1536 + ko / 2 + xq * 4];
      pt0 = *(const float4*)(tpa + ko);
      pt1 = *(const float4*)(tpb + ko);
    }
    bf16x8 ah[2], alo[2], bh[2], blo[2];
#pragma unroll
    for (int mi = 0; mi < 2; ++mi) {
      int r = 32 * wm + 16 * mi + lr;
      ah[mi] = *(const bf16x8*)&Ah[r * 20 + lg * 4];
      alo[mi] = *(const bf16x8*)&Al[r * 20 + lg * 4];
    }
#pragma unroll
    for (int ni = 0; ni < 2; ++ni) {
      int r = 32 * wn + 16 * ni + lr;
      bh[ni] = *(const bf16x8*)&Bh[r * 20 + lg * 4];
      blo[ni] = *(const bf16x8*)&Bl[r * 20 + lg * 4];
    }
#pragma unroll
    for (int mi = 0; mi < 2; ++mi)
#pragma unroll
      for (int ni = 0; ni < 2; ++ni) {
        acc[mi][ni] = __builtin_amdgcn_mfma_f32_16x16x32_bf16(ah[mi], bh[ni], acc[mi][ni], 0, 0, 0);
        acc[mi][ni] = __builtin_amdgcn_mfma_f32_16x16x32_bf16(ah[mi], blo[ni], acc[mi][ni], 0, 0, 0);
        acc[mi][ni] = __builtin_amdgcn_mfma_f32_16x16x32_bf16(alo[mi], bh[ni], acc[mi][ni], 0, 0, 0);
      }
  }

  // tr_sq reduce across the 8 k-slice lanes per row
  float s0 = sq0;
  s0 += __shfl_xor(s0, 1); s0 += __shfl_xor(s0, 2); s0 += __shfl_xor(s0, 4);
  float s1 = sq1;
  s1 += __shfl_xor(s1, 1); s1 += __shfl_xor(s1, 2); s1 += __shfl_xor(s1, 4);
  if ((tid & 7) == 0) {
    trsq_s[tn0] = s0;
    trsq_s[tn0 + 32] = s1;
  }
  __syncthreads();

  // epilogue: norm = cdeno*(xsq - 2a*cross + a^2*trsq); C/D frag: col=lane&15, row=4*lg+reg
#pragma unroll
  for (int mi = 0; mi < 2; ++mi) {
#pragma unroll
    for (int r = 0; r < 4; ++r) {
      const int b = 32 * wm + 16 * mi + 4 * lg + r;
      const float a_ = cAs[b], cd = cDs[b], xs = cXs[b];
      const float twoa = 2.f * a_, asq = a_ * a_;
#pragma unroll
      for (int ni = 0; ni < 2; ++ni) {
        const int ncol = 32 * wn + 16 * ni + lr;
        const int ng = n0 + ncol;
        const float nv = cd * (xs - twoa * acc[mi][ni][r] + asq * trsq_s[ncol]);
        wsf[OFF_NORM + (size_t)b * NPAD + ng] = (ng < CN) ? nv : -3.0e38f;
      }
    }
  }
}

// ---------------- Kernel 3: softmax -> W split to bf16 hi/lo planes ----------------
// grid (4, 64): each block re-scans the row for max, then exps its quarter.
__global__ __launch_bounds__(256) void softmax_kernel(float* __restrict__ wsf) {
  const int g = blockIdx.x, b = blockIdx.y, tid = threadIdx.x;
  const int lane = tid & 63, wv = tid >> 6;
  __shared__ float red[4];
  __shared__ float msh;

  const float4* rowf4 = (const float4*)(wsf + OFF_NORM + (size_t)b * NPAD);
  float m = -3.4e38f;
  for (int i = tid; i < NPAD / 4; i += 256) {
    float4 v = rowf4[i];
    m = fmaxf(m, fmaxf(fmaxf(v.x, v.y), fmaxf(v.z, v.w)));
  }
#pragma unroll
  for (int o = 1; o < 64; o <<= 1) m = fmaxf(m, __shfl_xor(m, o));
  if (lane == 0) red[wv] = m;
  __syncthreads();
  if (tid == 0) msh = fmaxf(fmaxf(red[0], red[1]), fmaxf(red[2], red[3]));
  __syncthreads();
  m = msh;
  __syncthreads();

  float4* q4 = (float4*)(wsf + OFF_NORM + (size_t)b * NPAD + (size_t)g * (NPAD / 4));
  unsigned int* whi32 = (unsigned int*)(wsf + OFF_WHI);
  unsigned int* wlo32 = (unsigned int*)(wsf + OFF_WLO);
  const size_t ub = (size_t)b * (NPAD / 2) + (size_t)g * (NPAD / 8);
  float s = 0.f;
  for (int i = tid; i < NPAD / 16; i += 256) {
    float4 v = q4[i];
    float4 e;
    e.x = __expf(v.x - m); e.y = __expf(v.y - m);
    e.z = __expf(v.z - m); e.w = __expf(v.w - m);
    s += (e.x + e.y) + (e.z + e.w);
    uint2 hi, lo;
    cvt_hl(e, hi, lo);
    *(uint2*)&whi32[ub + 2 * i] = hi;
    *(uint2*)&wlo32[ub + 2 * i] = lo;
  }
#pragma unroll
  for (int o = 1; o < 64; o <<= 1) s += __shfl_xor(s, o);
  if (lane == 0) red[wv] = s;
  __syncthreads();
  if (tid == 0) wsf[OFF_PSUM + 4 * b + g] = (red[0] + red[1]) + (red[2] + red[3]);
}

// ---------------- Kernel 4: partial = W @ train via split-bf16 MFMA ----------------
// grid (24 d-tiles, 32 n-chunks) = 768 blocks. Block: 64b x 128d, 4 waves 2x2 (32b x 64d).
// train transposed into LDS [d][n] during staging (strided-d mapping: ~4-way write aliasing).
__global__ __launch_bounds__(256, 3) void gemm2_kernel(
    const float* __restrict__ train, float* __restrict__ wsf) {
  __shared__ __align__(16) unsigned int Wh[64 * 20], Wl[64 * 20];
  __shared__ __align__(16) unsigned int Th[128 * 20], Tl[128 * 20];

  const int tid = threadIdx.x;
  const int d0 = blockIdx.x * TD2;
  const int g = blockIdx.y;
  const int nchunk = g * NC2;

  const unsigned int* wh32 = (const unsigned int*)(wsf + OFF_WHI);
  const unsigned int* wl32 = (const unsigned int*)(wsf + OFF_WLO);

  const int wr = tid >> 2, wq = tid & 3;    // W staging: row b, 16B-quad
  const int dq = tid & 31, ng = tid >> 5;   // T staging: d = dq+32c, n = 4*ng+r

  // prefetch k-tile 0
  uint4 pwh = *(const uint4*)&wh32[(size_t)wr * (NPAD / 2) + nchunk / 2 + wq * 4];
  uint4 pwl = *(const uint4*)&wl32[(size_t)wr * (NPAD / 2) + nchunk / 2 + wq * 4];
  float ptv[16];
#pragma unroll
  for (int r = 0; r < 4; ++r) {
    int n = nchunk + 4 * ng + r;
    if (n >= CN) n = 0;
#pragma unroll
    for (int c = 0; c < 4; ++c) ptv[4 * r + c] = train[(size_t)n * CD + d0 + dq + 32 * c];
  }

  f32x4 acc[2][4];
#pragma unroll
  for (int i = 0; i < 2; ++i)
#pragma unroll
    for (int j = 0; j < 4; ++j) acc[i][j] = (f32x4){0.f, 0.f, 0.f, 0.f};

  const int lane = tid & 63, w = tid >> 6;
  const int wm = w >> 1, wd = w & 1, lr = lane & 15, lg = lane >> 4;

  for (int kt = 0; kt < NK2; ++kt) {
    __syncthreads();
    *(uint4*)&Wh[wr * 20 + wq * 4] = pwh;
    *(uint4*)&Wl[wr * 20 + wq * 4] = pwl;
#pragma unroll
    for (int c = 0; c < 4; ++c) {
      __bf16 h0 = (__bf16)ptv[c], h1 = (__bf16)ptv[4 + c];
      __bf16 h2 = (__bf16)ptv[8 + c], h3 = (__bf16)ptv[12 + c];
      __bf16 l0 = (__bf16)(ptv[c] - (float)h0), l1 = (__bf16)(ptv[4 + c] - (float)h1);
      __bf16 l2 = (__bf16)(ptv[8 + c] - (float)h2), l3 = (__bf16)(ptv[12 + c] - (float)h3);
      *(uint2*)&Th[(dq + 32 * c) * 20 + 2 * ng] = make_uint2(pk(h0, h1), pk(h2, h3));
      *(uint2*)&Tl[(dq + 32 * c) * 20 + 2 * ng] = make_uint2(pk(l0, l1), pk(l2, l3));
    }
    __syncthreads();
    if (kt + 1 < NK2) {
      const int nb = nchunk + (kt + 1) * 32;
      pwh = *(const uint4*)&wh32[(size_t)wr * (NPAD / 2) + nb / 2 + wq * 4];
      pwl = *(const uint4*)&wl32[(size_t)wr * (NPAD / 2) + nb / 2 + wq * 4];
#pragma unroll
      for (int r = 0; r < 4; ++r) {
        int n = nb + 4 * ng + r;
        if (n >= CN) n = 0;
#pragma unroll
        for (int c = 0; c < 4; ++c) ptv[4 * r + c] = train[(size_t)n * CD + d0 + dq + 32 * c];
      }
    }
    bf16x8 ah[2], alo[2];
#pragma unroll
    for (int mi = 0; mi < 2; ++mi) {
      int r = 32 * wm + 16 * mi + lr;
      ah[mi] = *(const bf16x8*)&Wh[r * 20 + lg * 4];
      alo[mi] = *(const bf16x8*)&Wl[r * 20 + lg * 4];
    }
#pragma unroll
    for (int di = 0; di < 4; ++di) {
      int r = 64 * wd + 16 * di + lr;
      bf16x8 bh = *(const bf16x8*)&Th[r * 20 + lg * 4];
      bf16x8 bl = *(const bf16x8*)&Tl[r * 20 + lg * 4];
#pragma unroll
      for (int mi = 0; mi < 2; ++mi) {
        acc[mi][di] = __builtin_amdgcn_mfma_f32_16x16x32_bf16(ah[mi], bh, acc[mi][di], 0, 0, 0);
        acc[mi][di] = __builtin_amdgcn_mfma_f32_16x16x32_bf16(ah[mi], bl, acc[mi][di], 0, 0, 0);
        acc[mi][di] = __builtin_amdgcn_mfma_f32_16x16x32_bf16(alo[mi], bh, acc[mi][di], 0, 0, 0);
      }
    }
  }

  // store partials: C/D frag col=lr (d), row=4*lg+r (b)
#pragma unroll
  for (int mi = 0; mi < 2; ++mi)
#pragma unroll
    for (int r = 0; r < 4; ++r) {
      const int b = 32 * wm + 16 * mi + 4 * lg + r;
      float* dst = &wsf[OFF_P + ((size_t)g * CB + b) * CD + d0 + 64 * wd + lr];
#pragma unroll
      for (int di = 0; di < 4; ++di) dst[16 * di] = acc[mi][di][r];
    }
}

// ---------------- Kernel 5: reduce partials + finalize ----------------
__global__ __launch_bounds__(256) void finalize_kernel(
    const float* __restrict__ x, const float* __restrict__ wsf,
    float* __restrict__ out) {
  const int vi = blockIdx.x * 256 + threadIdx.x;  // float4 idx, 0..49151
  const int b = vi / (CD / 4);
  float4 s = make_float4(0.f, 0.f, 0.f, 0.f);
#pragma unroll 8
  for (int g = 0; g < G2; ++g) {
    const float4 p = *reinterpret_cast<const float4*>(
        &wsf[OFF_P + (size_t)g * CB * CD + 4 * (size_t)vi]);
    s.x += p.x; s.y += p.y; s.z += p.z; s.w += p.w;
  }
  const float l = (wsf[OFF_PSUM + 4 * b] + wsf[OFF_PSUM + 4 * b + 1]) +
                  (wsf[OFF_PSUM + 4 * b + 2] + wsf[OFF_PSUM + 4 * b + 3]);
  const float cx = wsf[OFF_CX + b];
  const float ch = wsf[OFF_CXH + b] / l;
  const float4 xv = *reinterpret_cast<const float4*>(&x[4 * (size_t)vi]);
  float4 o;
  o.x = cx * xv.x - ch * s.x;
  o.y = cx * xv.y - ch * s.y;
  o.z = cx * xv.z - ch * s.z;
  o.w = cx * xv.w - ch * s.w;
  *reinterpret_cast<float4*>(&out[4 * (size_t)vi]) = o;
}

extern "C" void kernel_launch(void* const* d_in, const int* in_sizes, int n_in,
                              void* d_out, int out_size, void* d_ws, size_t ws_size,
                              hipStream_t stream) {
  (void)in_sizes; (void)n_in; (void)out_size; (void)ws_size;
  const float* x = (const float*)d_in[0];
  const float* train = (const float*)d_in[1];
  const float* acp = (const float*)d_in[2];
  const int* t = (const int*)d_in[3];
  float* out = (float*)d_out;
  float* wsf = (float*)d_ws;

  prep_kernel<<<CB, 64, 0, stream>>>(x, acp, t, wsf);
  gemm1_kernel<<<NPAD / 64, 256, 0, stream>>>(train, wsf);
  softmax_kernel<<<dim3(4, CB), 256, 0, stream>>>(wsf);
  gemm2_kernel<<<dim3(CD / TD2, G2), 256, 0, stream>>>(train, wsf);
  finalize_kernel<<<(CB * CD / 4) / 256, 256, 0, stream>>>(x, wsf, out);
}